// Round 5
// baseline (1363.421 us; speedup 1.0000x reference)
//
#include <hip/hip_runtime.h>
#include <math.h>

#define NROWS 8192
#define DIM   512
#define HID1  1024
#define HID2  512
#define NCLS  10
#define KTOP  64
#define KPACK 1024      // packed row: [hi(512) | lo(512)]
#define KFULL 1536      // logical GEMM K: hi*hi + hi*lo + lo*hi
#define EPSBAND 0.02f   // d2 ambiguity half-band; approx err <= ~2e-3

typedef __attribute__((ext_vector_type(8))) short short8;
typedef __attribute__((ext_vector_type(4))) float f32x4;
typedef __attribute__((ext_vector_type(4))) double f64x4;

__device__ __forceinline__ unsigned short f2bf(float x) {
    unsigned u = __float_as_uint(x);
    u += 0x7FFFu + ((u >> 16) & 1u);   // RN-even
    return (unsigned short)(u >> 16);
}
__device__ __forceinline__ float bf2f(unsigned short h) {
    return __uint_as_float(((unsigned)h) << 16);
}

// ---------------- column stats (mean/var over batch), fp64 ----------------
template <typename T>
__global__ __launch_bounds__(256) void col_stats_partial(
    const T* __restrict__ A, int F, int rowsPerBlock,
    double* __restrict__ pSum, double* __restrict__ pSqs)
{
    int c  = blockIdx.x * 256 + threadIdx.x;
    int r0 = blockIdx.y * rowsPerBlock;
    double s = 0.0, s2 = 0.0;
    for (int r = r0; r < r0 + rowsPerBlock; ++r) {
        double v = (double)A[(size_t)r * F + c];
        s  += v;
        s2 += v * v;
    }
    pSum[(size_t)blockIdx.y * F + c] = s;
    pSqs[(size_t)blockIdx.y * F + c] = s2;
}

__global__ __launch_bounds__(256) void col_stats_final(
    const double* __restrict__ pSum, const double* __restrict__ pSqs,
    const float* __restrict__ g, const float* __restrict__ b,
    double* __restrict__ scale, double* __restrict__ shift, int F, int nPart)
{
    int c = blockIdx.x * 256 + threadIdx.x;
    double s = 0.0, s2 = 0.0;
    for (int p = 0; p < nPart; ++p) {
        s  += pSum[(size_t)p * F + c];
        s2 += pSqs[(size_t)p * F + c];
    }
    double mean = s * (1.0 / NROWS);
    double var  = s2 * (1.0 / NROWS) - mean * mean;
    double sc   = (double)g[c] / sqrt(var + 1e-5);
    scale[c] = sc;
    shift[c] = (double)b[c] - mean * sc;
}

// ---------------- f64-MFMA: out = tanh( affine(A) @ W^T + bias ), fp64 ----------------
// Tile 64(M)x64(N), 4 waves, K-chunk 32, reg-staged double-buffer (T14 async split):
// issue next-chunk global loads -> MFMA current chunk -> affine + ds_write next -> barrier.
// LDS k-major [k][67] (pitch 67: write conflicts 4-way -> free 2-way).
// 1D grid + bijective XCD swizzle: each XCD gets contiguous M-stripe x all F.
template <typename T>
__global__ __launch_bounds__(256) void gemm_mfma_tanh(
    const T* __restrict__ A, const double* __restrict__ scl, const double* __restrict__ sft,
    const float* __restrict__ W, const float* __restrict__ bias,
    double* __restrict__ out, int Kd, int F)
{
    __shared__ double aS[2][32 * 67];
    __shared__ double bS[2][32 * 67];
    const int t = threadIdx.x;
    const int lane = t & 63;
    const int wv = t >> 6;
    // XCD swizzle (nwg divisible by 8)
    const int nwg = gridDim.x;
    const int q = nwg >> 3;
    const int bid = blockIdx.x;
    const int wgid = (bid & 7) * q + (bid >> 3);
    const int fBlocks = F >> 6;
    const int mb = wgid / fBlocks;
    const int fb = wgid - mb * fBlocks;
    const int fBase = fb * 64;
    const int mBase = mb * 64;
    const int srow = t >> 2;          // 0..63 (M-row for A, N-col for B)
    const int skq  = (t & 3) * 8;     // k offset 0,8,16,24

    f64x4 acc[4];
    #pragma unroll
    for (int n = 0; n < 4; ++n) acc[n] = (f64x4){0.0, 0.0, 0.0, 0.0};

    T      areg[8];
    float  wreg[8];
    double sclr[8], sftr[8];

    auto stage_load = [&](int ch) {
        const int kb = ch << 5;
        const T* ap = &A[(size_t)(mBase + srow) * Kd + kb + skq];
        if constexpr (sizeof(T) == 4) {
            float4 x0 = *(const float4*)ap;
            float4 x1 = *(const float4*)(ap + 4);
            areg[0] = x0.x; areg[1] = x0.y; areg[2] = x0.z; areg[3] = x0.w;
            areg[4] = x1.x; areg[5] = x1.y; areg[6] = x1.z; areg[7] = x1.w;
        } else {
            const double2* dp = (const double2*)ap;
            double2 d0 = dp[0], d1 = dp[1], d2 = dp[2], d3 = dp[3];
            areg[0] = d0.x; areg[1] = d0.y; areg[2] = d1.x; areg[3] = d1.y;
            areg[4] = d2.x; areg[5] = d2.y; areg[6] = d3.x; areg[7] = d3.y;
        }
        const float4* wp = (const float4*)&W[(size_t)(fBase + srow) * Kd + kb + skq];
        float4 w0 = wp[0], w1 = wp[1];
        wreg[0] = w0.x; wreg[1] = w0.y; wreg[2] = w0.z; wreg[3] = w0.w;
        wreg[4] = w1.x; wreg[5] = w1.y; wreg[6] = w1.z; wreg[7] = w1.w;
        const double2* sp = (const double2*)&scl[kb + skq];
        const double2* hp = (const double2*)&sft[kb + skq];
        #pragma unroll
        for (int i = 0; i < 4; ++i) {
            double2 sv = sp[i], hv = hp[i];
            sclr[2 * i] = sv.x; sclr[2 * i + 1] = sv.y;
            sftr[2 * i] = hv.x; sftr[2 * i + 1] = hv.y;
        }
    };
    auto stage_write = [&](int buf) {
        #pragma unroll
        for (int i = 0; i < 8; ++i) {
            aS[buf][(skq + i) * 67 + srow] = (double)areg[i] * sclr[i] + sftr[i];
            bS[buf][(skq + i) * 67 + srow] = (double)wreg[i];
        }
    };
    auto compute = [&](int buf) {
        #pragma unroll
        for (int k4 = 0; k4 < 8; ++k4) {
            const int kk = k4 * 4 + (lane >> 4);
            double a = aS[buf][kk * 67 + wv * 16 + (lane & 15)];
            #pragma unroll
            for (int n = 0; n < 4; ++n) {
                double b = bS[buf][kk * 67 + n * 16 + (lane & 15)];
                acc[n] = __builtin_amdgcn_mfma_f64_16x16x4f64(a, b, acc[n], 0, 0, 0);
            }
        }
    };

    const int nChunks = Kd >> 5;
    stage_load(0);
    stage_write(0);
    __syncthreads();
    int cur = 0;
    for (int ch = 0; ch < nChunks; ++ch) {
        const bool hn = (ch + 1 < nChunks);
        if (hn) stage_load(ch + 1);      // issue early: latency hides under MFMA
        compute(cur);
        if (hn) stage_write(cur ^ 1);    // write late, other buffer
        __syncthreads();
        cur ^= 1;
    }

    // ---- epilogue: bias + tanh, fp64 store ----
    #pragma unroll
    for (int n = 0; n < 4; ++n) {
        const int f = fBase + n * 16 + (lane & 15);
        const double bz = (double)bias[f];
        #pragma unroll
        for (int r = 0; r < 4; ++r) {
            const int m = mBase + wv * 16 + (lane >> 4) * 4 + r;
            out[(size_t)m * F + f] = tanh(acc[n][r] + bz);
        }
    }
}

// ---------------- pack: f = y2*scl+sft (fp64) -> R=[hi|lo] bf16, sqf fp32 ----------------
__global__ __launch_bounds__(256) void pack_features(
    const double* __restrict__ y2, const double* __restrict__ scl, const double* __restrict__ sft,
    unsigned short* __restrict__ R, float* __restrict__ sqf)
{
    __shared__ double red[4];
    const int r = blockIdx.x;
    const int t = threadIdx.x;
    const int wid = t >> 6, lane = t & 63;
    const int c = t * 2;
    double2 y  = *(const double2*)&y2[(size_t)r * HID2 + c];
    double2 s2 = *(const double2*)&scl[c];
    double2 h2 = *(const double2*)&sft[c];
    double f0 = y.x * s2.x + h2.x;
    double f1 = y.y * s2.y + h2.y;
    unsigned short hi0 = f2bf((float)f0);
    unsigned short hi1 = f2bf((float)f1);
    unsigned short lo0 = f2bf((float)(f0 - (double)bf2f(hi0)));
    unsigned short lo1 = f2bf((float)(f1 - (double)bf2f(hi1)));
    unsigned short* Rr = R + (size_t)r * KPACK;
    Rr[c]           = hi0; Rr[c + 1]           = hi1;
    Rr[HID2 + c]    = lo0; Rr[HID2 + c + 1]    = lo1;
    double s = f0 * f0 + f1 * f1;
    #pragma unroll
    for (int off = 32; off > 0; off >>= 1) s += __shfl_down(s, off);
    if (lane == 0) red[wid] = s;
    __syncthreads();
    if (t == 0) sqf[r] = (float)(red[0] + red[1] + red[2] + red[3]);
}

// ---------------- sim chunk via bf16 MFMA, 2-phase double-buffered ----------------
// grid (8, 64): bx = i-block index space, by = j-block; flat bid XCD-swizzled so each
// XCD covers all 8 i-blocks x 8 j-blocks (A panel 2MB + B panels 2MB L2-resident).
__global__ __launch_bounds__(256) void sim_mfma(
    const unsigned short* __restrict__ R, const float* __restrict__ sqf,
    float* __restrict__ simbuf, int rowBase)
{
    __shared__ unsigned short aT[2][128 * 64];
    __shared__ unsigned short bT[2][128 * 64];
    const int t = threadIdx.x;
    const int wid = t >> 6, lane = t & 63;
    const int wr = wid >> 1, wc = wid & 1;
    const int bid  = blockIdx.y * 8 + blockIdx.x;   // 512 blocks
    const int wgid = (bid & 7) * 64 + (bid >> 3);   // XCD-contiguous chunks
    const int ib = wgid & 7;
    const int jb = wgid >> 3;
    const int iBase = rowBase + ib * 128;
    const int jBase = jb * 128;
    const int srow = lane >> 3;          // 0..7
    const int skk  = (lane & 7) * 8;     // k element offset within 64

    f32x4 zero = {0.f, 0.f, 0.f, 0.f};
    f32x4 acc[4][4];
    #pragma unroll
    for (int m = 0; m < 4; ++m)
        #pragma unroll
        for (int n = 0; n < 4; ++n) acc[m][n] = zero;

    auto STAGE = [&](int buf, int kt) {
        const int k0 = kt * 64;
        const int aSrc = (k0 < 512)  ? k0 : (k0 - 512);   // [hi, hi, lo]
        const int bSrc = (k0 < 1024) ? k0 : (k0 - 1024);  // [hi, lo, hi]
        #pragma unroll
        for (int c = 0; c < 4; ++c) {
            const int row = c * 32 + wid * 8 + srow;
            const unsigned short* gpA = R + (size_t)(iBase + row) * KPACK + aSrc + skk;
            const unsigned short* gpB = R + (size_t)(jBase + row) * KPACK + bSrc + skk;
            unsigned short* lpA = &aT[buf][(c * 4 + wid) * 512];  // wave-uniform base
            unsigned short* lpB = &bT[buf][(c * 4 + wid) * 512];
            __builtin_amdgcn_global_load_lds((const __attribute__((address_space(1))) void*)gpA,
                (__attribute__((address_space(3))) void*)lpA, 16, 0, 0);
            __builtin_amdgcn_global_load_lds((const __attribute__((address_space(1))) void*)gpB,
                (__attribute__((address_space(3))) void*)lpB, 16, 0, 0);
        }
    };

    STAGE(0, 0);
    __syncthreads();
    int cur = 0;
    const int nKT = KFULL / 64;   // 24
    for (int kt = 0; kt < nKT; ++kt) {
        if (kt + 1 < nKT) STAGE(cur ^ 1, kt + 1);   // in flight during MFMA below
        #pragma unroll
        for (int ks = 0; ks < 2; ++ks) {
            short8 aF[4], bF[4];
            #pragma unroll
            for (int m = 0; m < 4; ++m) {
                int rA = wr * 64 + m * 16 + (lane & 15);
                aF[m] = *(const short8*)&aT[cur][rA * 64 + ks * 32 + (lane >> 4) * 8];
            }
            #pragma unroll
            for (int n = 0; n < 4; ++n) {
                int rB = wc * 64 + n * 16 + (lane & 15);
                bF[n] = *(const short8*)&bT[cur][rB * 64 + ks * 32 + (lane >> 4) * 8];
            }
            #pragma unroll
            for (int m = 0; m < 4; ++m)
                #pragma unroll
                for (int n = 0; n < 4; ++n)
                    acc[m][n] = __builtin_amdgcn_mfma_f32_16x16x32_bf16(aF[m], bF[n], acc[m][n], 0, 0, 0);
        }
        __syncthreads();   // drains vmcnt: next buffer ready
        cur ^= 1;
    }

    #pragma unroll
    for (int m = 0; m < 4; ++m) {
        #pragma unroll
        for (int n = 0; n < 4; ++n) {
            int j = jBase + wc * 64 + n * 16 + (lane & 15);
            float sqj = sqf[j];
            #pragma unroll
            for (int r = 0; r < 4; ++r) {
                int i = iBase + wr * 64 + m * 16 + (lane >> 4) * 4 + r;
                float d2 = sqf[i] + sqj - 2.0f * acc[m][n][r];
                d2 = fmaxf(d2, 0.f);
                float s = (i == j) ? -INFINITY : -d2;
                simbuf[(size_t)(i - rowBase) * NROWS + j] = s;
            }
        }
    }
}

// ---------------- top-K (fp32 rank) + fp64 band refinement + softmax ----------------
__device__ __forceinline__ unsigned fKey(float v) {
    unsigned b = __float_as_uint(v);
    return (b & 0x80000000u) ? ~b : (b | 0x80000000u);
}
__device__ __forceinline__ float keyToFloat(unsigned k) {
    unsigned b = (k & 0x80000000u) ? (k ^ 0x80000000u) : ~k;
    return __uint_as_float(b);
}

__global__ __launch_bounds__(256) void topk_refine(
    const float* __restrict__ simbuf,
    const double* __restrict__ y2, const double* __restrict__ scl, const double* __restrict__ sft,
    const int* __restrict__ labels, float* __restrict__ out, int rowBase)
{
    __shared__ int      redI[4];
    __shared__ unsigned redU[4];
    __shared__ float    redF[4];
    __shared__ float    cls[NCLS];
    __shared__ int      bandJ[128];
    __shared__ double   bandD2[128];
    __shared__ unsigned char keepB[128];
    __shared__ int      bandCnt;

    const int t = threadIdx.x;
    const int wid = t >> 6, lane = t & 63;
    const int row = blockIdx.x;
    const int gi = rowBase + row;
    const float* srow = simbuf + (size_t)row * NROWS;

    unsigned key[32];
    #pragma unroll
    for (int ii = 0; ii < 32; ++ii) key[ii] = fKey(srow[t + ii * 256]);

    // global row max (nearest neighbor), fp32 approx — common softmax shift
    unsigned kmax = 0u;
    #pragma unroll
    for (int ii = 0; ii < 32; ++ii) kmax = max(kmax, key[ii]);
    #pragma unroll
    for (int off = 32; off > 0; off >>= 1) kmax = max(kmax, (unsigned)__shfl_down(kmax, off));
    if (lane == 0) redU[wid] = kmax;
    if (t == 0) bandCnt = 0;
    if (t < NCLS) cls[t] = 0.f;
    __syncthreads();
    kmax = max(max(redU[0], redU[1]), max(redU[2], redU[3]));
    float d2min = fmaxf(-keyToFloat(kmax), 0.f);
    float distMin = (d2min > 1e-9f) ? sqrtf(d2min) : 0.f;
    __syncthreads();

    // binary search: T64 = 64th largest fp32 key
    unsigned lo = 0u, hi = 0xFFFFFFFFu;
    while (lo < hi) {
        unsigned mid = (unsigned)(((unsigned long long)lo + hi + 1ull) >> 1);
        int cnt = 0;
        #pragma unroll
        for (int ii = 0; ii < 32; ++ii) cnt += (key[ii] >= mid) ? 1 : 0;
        #pragma unroll
        for (int off = 32; off > 0; off >>= 1) cnt += __shfl_down(cnt, off);
        if (lane == 0) redI[wid] = cnt;
        __syncthreads();
        int tot = redI[0] + redI[1] + redI[2] + redI[3];
        __syncthreads();
        if (tot >= KTOP) lo = mid; else hi = mid - 1u;
    }
    const float s64 = keyToFloat(lo);
    const unsigned Ku = fKey(s64 + EPSBAND);
    const unsigned Kl = fKey(s64 - EPSBAND);

    // nSafe = count(key >= Ku): definitely in true top-64
    int cnt = 0;
    #pragma unroll
    for (int ii = 0; ii < 32; ++ii) cnt += (key[ii] >= Ku) ? 1 : 0;
    #pragma unroll
    for (int off = 32; off > 0; off >>= 1) cnt += __shfl_down(cnt, off);
    if (lane == 0) redI[wid] = cnt;
    __syncthreads();
    const int nSafe = redI[0] + redI[1] + redI[2] + redI[3];
    const int Rslots = KTOP - nSafe;

    // collect ambiguous band: Kl <= key < Ku
    #pragma unroll
    for (int ii = 0; ii < 32; ++ii) {
        if (key[ii] >= Kl && key[ii] < Ku) {
            int pos = atomicAdd(&bandCnt, 1);
            if (pos < 128) bandJ[pos] = t + ii * 256;
        }
    }
    __syncthreads();
    const int nb = min(bandCnt, 128);

    // exact fp64 d2 for band members (one wave per member)
    for (int c2 = wid; c2 < nb; c2 += 4) {
        int j = bandJ[c2];
        double s = 0.0;
        for (int d = lane; d < HID2; d += 64) {
            double sc = scl[d], sh = sft[d];
            double fi = y2[(size_t)gi * HID2 + d] * sc + sh;
            double fj = y2[(size_t)j  * HID2 + d] * sc + sh;
            double df = fi - fj;
            s += df * df;
        }
        #pragma unroll
        for (int off = 32; off > 0; off >>= 1) s += __shfl_down(s, off);
        if (lane == 0) bandD2[c2] = s;
    }
    __syncthreads();

    // rank band by (d2 asc, index asc); keep top Rslots
    for (int c2 = t; c2 < nb; c2 += 256) {
        double d2c = bandD2[c2];
        int jc = bandJ[c2];
        int rank = 0;
        for (int q = 0; q < nb; ++q) {
            double dq = bandD2[q];
            rank += (dq < d2c || (dq == d2c && bandJ[q] < jc)) ? 1 : 0;
        }
        keepB[c2] = (rank < Rslots) ? 1 : 0;
    }
    __syncthreads();

    // softmax accumulate: safe set (fp32 d2) + kept band (fp64 d2)
    float S = 0.f;
    #pragma unroll
    for (int ii = 0; ii < 32; ++ii) {
        if (key[ii] >= Ku) {
            float d2 = -keyToFloat(key[ii]);
            float dist = (d2 > 1e-9f) ? sqrtf(d2) : 0.f;
            float w = expf(distMin - dist);
            S += w;
            atomicAdd(&cls[labels[t + ii * 256]], w);
        }
    }
    for (int c2 = t; c2 < nb; c2 += 256) {
        if (keepB[c2]) {
            double dd = bandD2[c2];
            float dist = (dd > 1e-9) ? (float)sqrt(dd) : 0.f;
            float w = expf(distMin - dist);
            S += w;
            atomicAdd(&cls[labels[bandJ[c2]]], w);
        }
    }
    #pragma unroll
    for (int off = 32; off > 0; off >>= 1) S += __shfl_down(S, off);
    if (lane == 0) redF[wid] = S;
    __syncthreads();
    float Stot = redF[0] + redF[1] + redF[2] + redF[3];

    if (t < NCLS) {
        float p = cls[t] / Stot;
        out[(size_t)gi * NCLS + t] = fminf(fmaxf(p, 0.f), 1.f);
    }
}

extern "C" void kernel_launch(void* const* d_in, const int* in_sizes, int n_in,
                              void* d_out, int out_size, void* d_ws, size_t ws_size,
                              hipStream_t stream)
{
    const float* x     = (const float*)d_in[0];
    // d_in[1] = x_n == x bit-exactly (self-neighbor mode) -> features computed once
    const int*   y_n   = (const int*)d_in[2];
    const float* ibn_g = (const float*)d_in[3];
    const float* ibn_b = (const float*)d_in[4];
    const float* W1    = (const float*)d_in[5];
    const float* b1    = (const float*)d_in[6];
    const float* g1    = (const float*)d_in[7];
    const float* bb1   = (const float*)d_in[8];
    const float* W2    = (const float*)d_in[9];
    const float* b2    = (const float*)d_in[10];
    const float* g2    = (const float*)d_in[11];
    const float* bb2   = (const float*)d_in[12];
    float* out = (float*)d_out;

    char* ws = (char*)d_ws;
    // [0,64 MiB): y1 fp64 during features; afterwards simbuf fp32 [0,32) + R bf16 [32,48)
    double*         y1   = (double*)(ws);
    float*          simb = (float*)(ws);
    unsigned short* Rp   = (unsigned short*)(ws + 33554432);
    double*         y2   = (double*)(ws + 67108864);        // 32 MiB, live to the end
    double*         pSum = (double*)(ws + 100663296);       // 512 KiB
    double*         pSqs = (double*)(ws + 101187584);       // 512 KiB
    double*         prm  = (double*)(ws + 101711872);       // 6*1024 f64
    double* scale0 = prm;           double* shift0 = prm + 1024;
    double* scale1 = prm + 2048;    double* shift1 = prm + 3072;
    double* scale2 = prm + 4096;    double* shift2 = prm + 5120;
    float*          sqf  = (float*)(ws + 101761024);        // 8192 f32

    dim3 blk(256);
    const int RPB = NROWS / 64;

    // input BN params
    col_stats_partial<float><<<dim3(DIM / 256, 64), blk, 0, stream>>>(x, DIM, RPB, pSum, pSqs);
    col_stats_final<<<dim3(DIM / 256), blk, 0, stream>>>(pSum, pSqs, ibn_g, ibn_b, scale0, shift0, DIM, 64);
    // layer 1 (f64 MFMA, 1D grid + XCD swizzle)
    gemm_mfma_tanh<float><<<dim3((NROWS / 64) * (HID1 / 64)), blk, 0, stream>>>(x, scale0, shift0, W1, b1, y1, DIM, HID1);
    col_stats_partial<double><<<dim3(HID1 / 256, 64), blk, 0, stream>>>(y1, HID1, RPB, pSum, pSqs);
    col_stats_final<<<dim3(HID1 / 256), blk, 0, stream>>>(pSum, pSqs, g1, bb1, scale1, shift1, HID1, 64);
    // layer 2 (f64 MFMA)
    gemm_mfma_tanh<double><<<dim3((NROWS / 64) * (HID2 / 64)), blk, 0, stream>>>(y1, scale1, shift1, W2, b2, y2, HID1, HID2);
    col_stats_partial<double><<<dim3(HID2 / 256, 64), blk, 0, stream>>>(y2, HID2, RPB, pSum, pSqs);
    col_stats_final<<<dim3(HID2 / 256), blk, 0, stream>>>(pSum, pSqs, g2, bb2, scale2, shift2, HID2, 64);
    // pack split-bf16 features + fp32 row norms (y1 now dead; R lives in its region)
    pack_features<<<dim3(NROWS), blk, 0, stream>>>(y2, scale2, shift2, Rp, sqf);
    // chunked MFMA sim + topk with fp64 band refinement
    for (int ch = 0; ch < 8; ++ch) {
        int rowBase = ch * 1024;
        sim_mfma<<<dim3(8, 64), blk, 0, stream>>>(Rp, sqf, simb, rowBase);
        topk_refine<<<dim3(1024), blk, 0, stream>>>(simb, y2, scale2, shift2, y_n, out, rowBase);
    }
}

// Round 6
// 1221.316 us; speedup vs baseline: 1.1164x; 1.1164x over previous
//
#include <hip/hip_runtime.h>
#include <math.h>

#define NROWS 8192
#define DIM   512
#define HID1  1024
#define HID2  512
#define NCLS  10
#define KTOP  64
#define KPACK 1024      // packed row: [hi(512) | lo(512)]
#define KFULL 1536      // logical GEMM K: hi*hi + hi*lo + lo*hi
#define EPSBAND 0.02f   // d2 ambiguity half-band; approx err <= ~2e-3

typedef __attribute__((ext_vector_type(8))) short short8;
typedef __attribute__((ext_vector_type(4))) float f32x4;
typedef __attribute__((ext_vector_type(4))) double f64x4;

__device__ __forceinline__ unsigned short f2bf(float x) {
    unsigned u = __float_as_uint(x);
    u += 0x7FFFu + ((u >> 16) & 1u);   // RN-even
    return (unsigned short)(u >> 16);
}
__device__ __forceinline__ float bf2f(unsigned short h) {
    return __uint_as_float(((unsigned)h) << 16);
}

// ---------------- column stats (mean/var over batch), fp64 ----------------
template <typename T>
__global__ __launch_bounds__(256) void col_stats_partial(
    const T* __restrict__ A, int F, int rowsPerBlock,
    double* __restrict__ pSum, double* __restrict__ pSqs)
{
    int c  = blockIdx.x * 256 + threadIdx.x;
    int r0 = blockIdx.y * rowsPerBlock;
    double s = 0.0, s2 = 0.0;
    for (int r = r0; r < r0 + rowsPerBlock; ++r) {
        double v = (double)A[(size_t)r * F + c];
        s  += v;
        s2 += v * v;
    }
    pSum[(size_t)blockIdx.y * F + c] = s;
    pSqs[(size_t)blockIdx.y * F + c] = s2;
}

__global__ __launch_bounds__(256) void col_stats_final(
    const double* __restrict__ pSum, const double* __restrict__ pSqs,
    const float* __restrict__ g, const float* __restrict__ b,
    double* __restrict__ scale, double* __restrict__ shift, int F, int nPart)
{
    int c = blockIdx.x * 256 + threadIdx.x;
    double s = 0.0, s2 = 0.0;
    for (int p = 0; p < nPart; ++p) {
        s  += pSum[(size_t)p * F + c];
        s2 += pSqs[(size_t)p * F + c];
    }
    double mean = s * (1.0 / NROWS);
    double var  = s2 * (1.0 / NROWS) - mean * mean;
    double sc   = (double)g[c] / sqrt(var + 1e-5);
    scale[c] = sc;
    shift[c] = (double)b[c] - mean * sc;
}

// ---------------- f64-MFMA: out = tanh( affine(A) @ W^T + bias ), fp64 ----------------
// Tile 64(M)x64(N), 4 waves, K-chunk 32. SINGLE 34KB LDS buffer (4 blocks/CU) with
// register double-buffer: issue loads(t+1) -> compute(t) -> barrier -> ds_write(t+1)
// -> barrier. Global latency hides under the ~2048-cyc MFMA block; barrier gaps hide
// under 4-blocks/CU TLP. LDS k-major [k][67].
template <typename T>
__global__ __launch_bounds__(256) void gemm_mfma_tanh(
    const T* __restrict__ A, const double* __restrict__ scl, const double* __restrict__ sft,
    const float* __restrict__ W, const float* __restrict__ bias,
    double* __restrict__ out, int Kd, int F)
{
    __shared__ double aS[32 * 67];
    __shared__ double bS[32 * 67];
    const int t = threadIdx.x;
    const int lane = t & 63;
    const int wv = t >> 6;
    // bijective XCD swizzle (nwg divisible by 8)
    const int nwg = gridDim.x;
    const int q = nwg >> 3;
    const int bid = blockIdx.x;
    const int wgid = (bid & 7) * q + (bid >> 3);
    const int fBlocks = F >> 6;
    const int mb = wgid / fBlocks;
    const int fb = wgid - mb * fBlocks;
    const int fBase = fb * 64;
    const int mBase = mb * 64;
    const int srow = t >> 2;          // 0..63 (M-row for A, N-col for B)
    const int skq  = (t & 3) * 8;     // k offset 0,8,16,24

    f64x4 acc[4];
    #pragma unroll
    for (int n = 0; n < 4; ++n) acc[n] = (f64x4){0.0, 0.0, 0.0, 0.0};

    T      areg[8];
    float  wreg[8];
    double sclr[8], sftr[8];

    auto stage_load = [&](int ch) {
        const int kb = ch << 5;
        const T* ap = &A[(size_t)(mBase + srow) * Kd + kb + skq];
        if constexpr (sizeof(T) == 4) {
            float4 x0 = *(const float4*)ap;
            float4 x1 = *(const float4*)(ap + 4);
            areg[0] = x0.x; areg[1] = x0.y; areg[2] = x0.z; areg[3] = x0.w;
            areg[4] = x1.x; areg[5] = x1.y; areg[6] = x1.z; areg[7] = x1.w;
        } else {
            const double2* dp = (const double2*)ap;
            double2 d0 = dp[0], d1 = dp[1], d2 = dp[2], d3 = dp[3];
            areg[0] = d0.x; areg[1] = d0.y; areg[2] = d1.x; areg[3] = d1.y;
            areg[4] = d2.x; areg[5] = d2.y; areg[6] = d3.x; areg[7] = d3.y;
        }
        const float4* wp = (const float4*)&W[(size_t)(fBase + srow) * Kd + kb + skq];
        float4 w0 = wp[0], w1 = wp[1];
        wreg[0] = w0.x; wreg[1] = w0.y; wreg[2] = w0.z; wreg[3] = w0.w;
        wreg[4] = w1.x; wreg[5] = w1.y; wreg[6] = w1.z; wreg[7] = w1.w;
        const double2* sp = (const double2*)&scl[kb + skq];
        const double2* hp = (const double2*)&sft[kb + skq];
        #pragma unroll
        for (int i = 0; i < 4; ++i) {
            double2 sv = sp[i], hv = hp[i];
            sclr[2 * i] = sv.x; sclr[2 * i + 1] = sv.y;
            sftr[2 * i] = hv.x; sftr[2 * i + 1] = hv.y;
        }
    };
    auto stage_write = [&]() {
        #pragma unroll
        for (int i = 0; i < 8; ++i) {
            aS[(skq + i) * 67 + srow] = (double)areg[i] * sclr[i] + sftr[i];
            bS[(skq + i) * 67 + srow] = (double)wreg[i];
        }
    };
    auto compute = [&]() {
        #pragma unroll
        for (int k4 = 0; k4 < 8; ++k4) {
            const int kk = k4 * 4 + (lane >> 4);
            double a = aS[kk * 67 + wv * 16 + (lane & 15)];
            #pragma unroll
            for (int n = 0; n < 4; ++n) {
                double b = bS[kk * 67 + n * 16 + (lane & 15)];
                acc[n] = __builtin_amdgcn_mfma_f64_16x16x4f64(a, b, acc[n], 0, 0, 0);
            }
        }
    };

    const int nChunks = Kd >> 5;
    stage_load(0);
    stage_write();
    __syncthreads();
    for (int ch = 0; ch < nChunks; ++ch) {
        const bool hn = (ch + 1 < nChunks);
        if (hn) stage_load(ch + 1);    // VMEM in flight under the MFMA block
        compute();
        __syncthreads();               // everyone done reading buffer
        if (hn) {
            stage_write();             // regs -> LDS for next chunk
            __syncthreads();
        }
    }

    // ---- epilogue: bias + tanh, fp64 store ----
    #pragma unroll
    for (int n = 0; n < 4; ++n) {
        const int f = fBase + n * 16 + (lane & 15);
        const double bz = (double)bias[f];
        #pragma unroll
        for (int r = 0; r < 4; ++r) {
            const int m = mBase + wv * 16 + (lane >> 4) * 4 + r;
            out[(size_t)m * F + f] = tanh(acc[n][r] + bz);
        }
    }
}

// ---------------- pack: f = y2*scl+sft (fp64) -> R=[hi|lo] bf16, sqf fp32 ----------------
__global__ __launch_bounds__(256) void pack_features(
    const double* __restrict__ y2, const double* __restrict__ scl, const double* __restrict__ sft,
    unsigned short* __restrict__ R, float* __restrict__ sqf)
{
    __shared__ double red[4];
    const int r = blockIdx.x;
    const int t = threadIdx.x;
    const int wid = t >> 6, lane = t & 63;
    const int c = t * 2;
    double2 y  = *(const double2*)&y2[(size_t)r * HID2 + c];
    double2 s2 = *(const double2*)&scl[c];
    double2 h2 = *(const double2*)&sft[c];
    double f0 = y.x * s2.x + h2.x;
    double f1 = y.y * s2.y + h2.y;
    unsigned short hi0 = f2bf((float)f0);
    unsigned short hi1 = f2bf((float)f1);
    unsigned short lo0 = f2bf((float)(f0 - (double)bf2f(hi0)));
    unsigned short lo1 = f2bf((float)(f1 - (double)bf2f(hi1)));
    unsigned short* Rr = R + (size_t)r * KPACK;
    Rr[c]           = hi0; Rr[c + 1]           = hi1;
    Rr[HID2 + c]    = lo0; Rr[HID2 + c + 1]    = lo1;
    double s = f0 * f0 + f1 * f1;
    #pragma unroll
    for (int off = 32; off > 0; off >>= 1) s += __shfl_down(s, off);
    if (lane == 0) red[wid] = s;
    __syncthreads();
    if (t == 0) sqf[r] = (float)(red[0] + red[1] + red[2] + red[3]);
}

// ---------------- sim chunk via bf16 MFMA, 2-phase dbuf + T2 XOR swizzle ----------------
// Rule 21: global_load_lds writes linearly, so the SOURCE address is pre-swizzled
// (chunk ^= row&7) and the ds_read applies the same XOR. Read conflicts 16-way -> 2-way.
__global__ __launch_bounds__(256) void sim_mfma(
    const unsigned short* __restrict__ R, const float* __restrict__ sqf,
    float* __restrict__ simbuf, int rowBase)
{
    __shared__ unsigned short aT[2][128 * 64];
    __shared__ unsigned short bT[2][128 * 64];
    const int t = threadIdx.x;
    const int wid = t >> 6, lane = t & 63;
    const int wr = wid >> 1, wc = wid & 1;
    const int bid  = blockIdx.y * 8 + blockIdx.x;   // 512 blocks
    const int wgid = (bid & 7) * 64 + (bid >> 3);   // XCD-contiguous chunks
    const int ib = wgid & 7;
    const int jb = wgid >> 3;
    const int iBase = rowBase + ib * 128;
    const int jBase = jb * 128;
    const int srow = lane >> 3;                     // 0..7 == row&7 at stage
    const int skk  = (((lane & 7) ^ srow) * 8);     // pre-swizzled 16B chunk in row

    f32x4 zero = {0.f, 0.f, 0.f, 0.f};
    f32x4 acc[4][4];
    #pragma unroll
    for (int m = 0; m < 4; ++m)
        #pragma unroll
        for (int n = 0; n < 4; ++n) acc[m][n] = zero;

    auto STAGE = [&](int buf, int kt) {
        const int k0 = kt * 64;
        const int aSrc = (k0 < 512)  ? k0 : (k0 - 512);   // [hi, hi, lo]
        const int bSrc = (k0 < 1024) ? k0 : (k0 - 1024);  // [hi, lo, hi]
        #pragma unroll
        for (int c = 0; c < 4; ++c) {
            const int row = c * 32 + wid * 8 + srow;
            const unsigned short* gpA = R + (size_t)(iBase + row) * KPACK + aSrc + skk;
            const unsigned short* gpB = R + (size_t)(jBase + row) * KPACK + bSrc + skk;
            unsigned short* lpA = &aT[buf][(c * 4 + wid) * 512];  // wave-uniform base
            unsigned short* lpB = &bT[buf][(c * 4 + wid) * 512];
            __builtin_amdgcn_global_load_lds((const __attribute__((address_space(1))) void*)gpA,
                (__attribute__((address_space(3))) void*)lpA, 16, 0, 0);
            __builtin_amdgcn_global_load_lds((const __attribute__((address_space(1))) void*)gpB,
                (__attribute__((address_space(3))) void*)lpB, 16, 0, 0);
        }
    };

    STAGE(0, 0);
    __syncthreads();
    int cur = 0;
    const int nKT = KFULL / 64;   // 24
    for (int kt = 0; kt < nKT; ++kt) {
        if (kt + 1 < nKT) STAGE(cur ^ 1, kt + 1);   // in flight during MFMA below
        #pragma unroll
        for (int ks = 0; ks < 2; ++ks) {
            short8 aF[4], bF[4];
            #pragma unroll
            for (int m = 0; m < 4; ++m) {
                int rA = wr * 64 + m * 16 + (lane & 15);
                int ck = ((ks * 4 + (lane >> 4)) ^ (lane & 7)) * 8;   // un-swizzle
                aF[m] = *(const short8*)&aT[cur][rA * 64 + ck];
            }
            #pragma unroll
            for (int n = 0; n < 4; ++n) {
                int rB = wc * 64 + n * 16 + (lane & 15);
                int ck = ((ks * 4 + (lane >> 4)) ^ (lane & 7)) * 8;
                bF[n] = *(const short8*)&bT[cur][rB * 64 + ck];
            }
            #pragma unroll
            for (int m = 0; m < 4; ++m)
                #pragma unroll
                for (int n = 0; n < 4; ++n)
                    acc[m][n] = __builtin_amdgcn_mfma_f32_16x16x32_bf16(aF[m], bF[n], acc[m][n], 0, 0, 0);
        }
        __syncthreads();   // drains vmcnt: next buffer ready
        cur ^= 1;
    }

    #pragma unroll
    for (int m = 0; m < 4; ++m) {
        #pragma unroll
        for (int n = 0; n < 4; ++n) {
            int j = jBase + wc * 64 + n * 16 + (lane & 15);
            float sqj = sqf[j];
            #pragma unroll
            for (int r = 0; r < 4; ++r) {
                int i = iBase + wr * 64 + m * 16 + (lane >> 4) * 4 + r;
                float d2 = sqf[i] + sqj - 2.0f * acc[m][n][r];
                d2 = fmaxf(d2, 0.f);
                float s = (i == j) ? -INFINITY : -d2;
                simbuf[(size_t)(i - rowBase) * NROWS + j] = s;
            }
        }
    }
}

// ---------------- top-K (fp32 rank) + fp64 band refinement + softmax ----------------
__device__ __forceinline__ unsigned fKey(float v) {
    unsigned b = __float_as_uint(v);
    return (b & 0x80000000u) ? ~b : (b | 0x80000000u);
}
__device__ __forceinline__ float keyToFloat(unsigned k) {
    unsigned b = (k & 0x80000000u) ? (k ^ 0x80000000u) : ~k;
    return __uint_as_float(b);
}

__global__ __launch_bounds__(256) void topk_refine(
    const float* __restrict__ simbuf,
    const double* __restrict__ y2, const double* __restrict__ scl, const double* __restrict__ sft,
    const int* __restrict__ labels, float* __restrict__ out, int rowBase)
{
    __shared__ int      redI[4];
    __shared__ unsigned redU[4];
    __shared__ float    redF[4];
    __shared__ float    cls[NCLS];
    __shared__ int      bandJ[128];
    __shared__ double   bandD2[128];
    __shared__ unsigned char keepB[128];
    __shared__ int      bandCnt;

    const int t = threadIdx.x;
    const int wid = t >> 6, lane = t & 63;
    const int row = blockIdx.x;
    const int gi = rowBase + row;
    const float* srow = simbuf + (size_t)row * NROWS;

    unsigned key[32];
    #pragma unroll
    for (int ii = 0; ii < 32; ++ii) key[ii] = fKey(srow[t + ii * 256]);

    // global row max (nearest neighbor), fp32 approx — common softmax shift
    unsigned kmax = 0u;
    #pragma unroll
    for (int ii = 0; ii < 32; ++ii) kmax = max(kmax, key[ii]);
    #pragma unroll
    for (int off = 32; off > 0; off >>= 1) kmax = max(kmax, (unsigned)__shfl_down(kmax, off));
    if (lane == 0) redU[wid] = kmax;
    if (t == 0) bandCnt = 0;
    if (t < NCLS) cls[t] = 0.f;
    __syncthreads();
    kmax = max(max(redU[0], redU[1]), max(redU[2], redU[3]));
    float d2min = fmaxf(-keyToFloat(kmax), 0.f);
    float distMin = (d2min > 1e-9f) ? sqrtf(d2min) : 0.f;
    __syncthreads();

    // binary search: T64 = 64th largest fp32 key
    unsigned lo = 0u, hi = 0xFFFFFFFFu;
    while (lo < hi) {
        unsigned mid = (unsigned)(((unsigned long long)lo + hi + 1ull) >> 1);
        int cnt = 0;
        #pragma unroll
        for (int ii = 0; ii < 32; ++ii) cnt += (key[ii] >= mid) ? 1 : 0;
        #pragma unroll
        for (int off = 32; off > 0; off >>= 1) cnt += __shfl_down(cnt, off);
        if (lane == 0) redI[wid] = cnt;
        __syncthreads();
        int tot = redI[0] + redI[1] + redI[2] + redI[3];
        __syncthreads();
        if (tot >= KTOP) lo = mid; else hi = mid - 1u;
    }
    const float s64 = keyToFloat(lo);
    const unsigned Ku = fKey(s64 + EPSBAND);
    const unsigned Kl = fKey(s64 - EPSBAND);

    // nSafe = count(key >= Ku): definitely in true top-64
    int cnt = 0;
    #pragma unroll
    for (int ii = 0; ii < 32; ++ii) cnt += (key[ii] >= Ku) ? 1 : 0;
    #pragma unroll
    for (int off = 32; off > 0; off >>= 1) cnt += __shfl_down(cnt, off);
    if (lane == 0) redI[wid] = cnt;
    __syncthreads();
    const int nSafe = redI[0] + redI[1] + redI[2] + redI[3];
    const int Rslots = KTOP - nSafe;

    // collect ambiguous band: Kl <= key < Ku
    #pragma unroll
    for (int ii = 0; ii < 32; ++ii) {
        if (key[ii] >= Kl && key[ii] < Ku) {
            int pos = atomicAdd(&bandCnt, 1);
            if (pos < 128) bandJ[pos] = t + ii * 256;
        }
    }
    __syncthreads();
    const int nb = min(bandCnt, 128);

    // exact fp64 d2 for band members (one wave per member)
    for (int c2 = wid; c2 < nb; c2 += 4) {
        int j = bandJ[c2];
        double s = 0.0;
        for (int d = lane; d < HID2; d += 64) {
            double sc = scl[d], sh = sft[d];
            double fi = y2[(size_t)gi * HID2 + d] * sc + sh;
            double fj = y2[(size_t)j  * HID2 + d] * sc + sh;
            double df = fi - fj;
            s += df * df;
        }
        #pragma unroll
        for (int off = 32; off > 0; off >>= 1) s += __shfl_down(s, off);
        if (lane == 0) bandD2[c2] = s;
    }
    __syncthreads();

    // rank band by (d2 asc, index asc); keep top Rslots
    for (int c2 = t; c2 < nb; c2 += 256) {
        double d2c = bandD2[c2];
        int jc = bandJ[c2];
        int rank = 0;
        for (int q = 0; q < nb; ++q) {
            double dq = bandD2[q];
            rank += (dq < d2c || (dq == d2c && bandJ[q] < jc)) ? 1 : 0;
        }
        keepB[c2] = (rank < Rslots) ? 1 : 0;
    }
    __syncthreads();

    // softmax accumulate: safe set (fp32 d2) + kept band (fp64 d2)
    float S = 0.f;
    #pragma unroll
    for (int ii = 0; ii < 32; ++ii) {
        if (key[ii] >= Ku) {
            float d2 = -keyToFloat(key[ii]);
            float dist = (d2 > 1e-9f) ? sqrtf(d2) : 0.f;
            float w = expf(distMin - dist);
            S += w;
            atomicAdd(&cls[labels[t + ii * 256]], w);
        }
    }
    for (int c2 = t; c2 < nb; c2 += 256) {
        if (keepB[c2]) {
            double dd = bandD2[c2];
            float dist = (dd > 1e-9) ? (float)sqrt(dd) : 0.f;
            float w = expf(distMin - dist);
            S += w;
            atomicAdd(&cls[labels[bandJ[c2]]], w);
        }
    }
    #pragma unroll
    for (int off = 32; off > 0; off >>= 1) S += __shfl_down(S, off);
    if (lane == 0) redF[wid] = S;
    __syncthreads();
    float Stot = redF[0] + redF[1] + redF[2] + redF[3];

    if (t < NCLS) {
        float p = cls[t] / Stot;
        out[(size_t)gi * NCLS + t] = fminf(fmaxf(p, 0.f), 1.f);
    }
}

extern "C" void kernel_launch(void* const* d_in, const int* in_sizes, int n_in,
                              void* d_out, int out_size, void* d_ws, size_t ws_size,
                              hipStream_t stream)
{
    const float* x     = (const float*)d_in[0];
    // d_in[1] = x_n == x bit-exactly (self-neighbor mode) -> features computed once
    const int*   y_n   = (const int*)d_in[2];
    const float* ibn_g = (const float*)d_in[3];
    const float* ibn_b = (const float*)d_in[4];
    const float* W1    = (const float*)d_in[5];
    const float* b1    = (const float*)d_in[6];
    const float* g1    = (const float*)d_in[7];
    const float* bb1   = (const float*)d_in[8];
    const float* W2    = (const float*)d_in[9];
    const float* b2    = (const float*)d_in[10];
    const float* g2    = (const float*)d_in[11];
    const float* bb2   = (const float*)d_in[12];
    float* out = (float*)d_out;

    char* ws = (char*)d_ws;
    // [0,64 MiB): y1 fp64 during features; afterwards simbuf fp32 [0,32) + R bf16 [32,48)
    double*         y1   = (double*)(ws);
    float*          simb = (float*)(ws);
    unsigned short* Rp   = (unsigned short*)(ws + 33554432);
    double*         y2   = (double*)(ws + 67108864);        // 32 MiB, live to the end
    double*         pSum = (double*)(ws + 100663296);       // 512 KiB
    double*         pSqs = (double*)(ws + 101187584);       // 512 KiB
    double*         prm  = (double*)(ws + 101711872);       // 6*1024 f64
    double* scale0 = prm;           double* shift0 = prm + 1024;
    double* scale1 = prm + 2048;    double* shift1 = prm + 3072;
    double* scale2 = prm + 4096;    double* shift2 = prm + 5120;
    float*          sqf  = (float*)(ws + 101761024);        // 8192 f32

    dim3 blk(256);
    const int RPB = NROWS / 64;

    // input BN params
    col_stats_partial<float><<<dim3(DIM / 256, 64), blk, 0, stream>>>(x, DIM, RPB, pSum, pSqs);
    col_stats_final<<<dim3(DIM / 256), blk, 0, stream>>>(pSum, pSqs, ibn_g, ibn_b, scale0, shift0, DIM, 64);
    // layer 1 (f64 MFMA, 1D grid + XCD swizzle)
    gemm_mfma_tanh<float><<<dim3((NROWS / 64) * (HID1 / 64)), blk, 0, stream>>>(x, scale0, shift0, W1, b1, y1, DIM, HID1);
    col_stats_partial<double><<<dim3(HID1 / 256, 64), blk, 0, stream>>>(y1, HID1, RPB, pSum, pSqs);
    col_stats_final<<<dim3(HID1 / 256), blk, 0, stream>>>(pSum, pSqs, g1, bb1, scale1, shift1, HID1, 64);
    // layer 2 (f64 MFMA)
    gemm_mfma_tanh<double><<<dim3((NROWS / 64) * (HID2 / 64)), blk, 0, stream>>>(y1, scale1, shift1, W2, b2, y2, HID1, HID2);
    col_stats_partial<double><<<dim3(HID2 / 256, 64), blk, 0, stream>>>(y2, HID2, RPB, pSum, pSqs);
    col_stats_final<<<dim3(HID2 / 256), blk, 0, stream>>>(pSum, pSqs, g2, bb2, scale2, shift2, HID2, 64);
    // pack split-bf16 features + fp32 row norms (y1 now dead; R lives in its region)
    pack_features<<<dim3(NROWS), blk, 0, stream>>>(y2, scale2, shift2, Rp, sqf);
    // chunked MFMA sim + topk with fp64 band refinement
    for (int ch = 0; ch < 8; ++ch) {
        int rowBase = ch * 1024;
        sim_mfma<<<dim3(8, 64), blk, 0, stream>>>(Rp, sqf, simb, rowBase);
        topk_refine<<<dim3(1024), blk, 0, stream>>>(simb, y2, scale2, shift2, y_n, out, rowBase);
    }
}